// Round 3
// baseline (237.250 us; speedup 1.0000x reference)
//
#include <hip/hip_runtime.h>
#include <math.h>

#define HIDDEN 2048
#define NEXP   64
#define BK     64           // k-chunk of W staged in LDS
#define NK4    (BK/4)       // 16 float4 steps per chunk
#define NCHUNK (HIDDEN/BK)  // 32
#define TPB    512          // 8 waves
#define TPW    8            // tokens per wave
#define TPBK   64           // tokens per block

typedef __attribute__((address_space(3))) unsigned int       lds_u32;
typedef __attribute__((address_space(1))) const unsigned int gbl_u32;

__global__ __launch_bounds__(TPB, 4)
void router_kernel(const float* __restrict__ x,
                   const float* __restrict__ Wg,
                   const float* __restrict__ gb,
                   float* __restrict__ out, int T)
{
  // W chunk [k4][expert] float4: per-lane ds_read_b128, lane-contiguous,
  // conflict-free. Double-buffered, staged via global_load_lds (no VGPR cost).
  // x is NOT staged: all its indices are wave-uniform -> scalar loads
  // (s_load_dwordx4) on the scalar pipe, keeping the LDS pipe ~free.
  __shared__ float4 wlds[2][NK4][NEXP];        // 32 KB

  const int tid  = threadIdx.x;
  const int lane = tid & 63;
  const int wid  = __builtin_amdgcn_readfirstlane(tid >> 6);
  const int tok0 = __builtin_amdgcn_readfirstlane((int)blockIdx.x * TPBK + wid * TPW);

  float  acc[TPW];   // per-chunk fp32 accumulator (lane = expert)
  double dacc[TPW];  // fp64 chunk fold: keeps total error ~3e-7, protects top-2 rank
#pragma unroll
  for (int t = 0; t < TPW; ++t) { acc[t] = 0.f; dacc[t] = 0.0; }

  auto stageW = [&](int buf, int k0) {
#pragma unroll
    for (int j = 0; j < 2; ++j) {
      const int s  = tid + j * TPB;          // 0..1023: k4 = s>>6, e = s&63
      const int e  = s & 63, k4 = s >> 6;
      __builtin_amdgcn_global_load_lds(
          (gbl_u32*)&Wg[(size_t)e * HIDDEN + k0 + 4 * k4],
          (lds_u32*)&wlds[buf][k4][e], 16, 0, 0);
    }
  };

  stageW(0, 0);
  __syncthreads();

  int cur = 0;
  for (int c = 0; c < NCHUNK; ++c) {
    if (c + 1 < NCHUNK) stageW(cur ^ 1, (c + 1) * BK);

    const size_t xbase = (size_t)tok0 * HIDDEN + c * BK;
#pragma unroll
    for (int k4 = 0; k4 < NK4; ++k4) {
      const float4 w = wlds[cur][k4][lane];  // lane = expert, per-lane b128
#pragma unroll
      for (int t = 0; t < TPW; ++t) {
        // fully wave-uniform address -> s_load_dwordx4 (scalar pipe)
        const float4 xv = *(const float4*)&x[xbase + (size_t)t * HIDDEN + 4 * k4];
        acc[t] = fmaf(xv.x, w.x, acc[t]);
        acc[t] = fmaf(xv.y, w.y, acc[t]);
        acc[t] = fmaf(xv.z, w.z, acc[t]);
        acc[t] = fmaf(xv.w, w.w, acc[t]);
      }
    }

#pragma unroll
    for (int t = 0; t < TPW; ++t) { dacc[t] += (double)acc[t]; acc[t] = 0.f; }

    __syncthreads();   // drains stageW vmcnt + orders W buffer reuse
    cur ^= 1;
  }

  // ---- epilogue: bias, wave top-2 (lane = expert), softmax over 2 ----
  const float bv = gb[lane];
#pragma unroll
  for (int t = 0; t < TPW; ++t) {
    const float v = (float)dacc[t] + bv;

    float v1 = v; int i1 = lane;
#pragma unroll
    for (int off = 32; off >= 1; off >>= 1) {
      const float ov = __shfl_xor(v1, off, 64);
      const int   oi = __shfl_xor(i1, off, 64);
      if (ov > v1 || (ov == v1 && oi < i1)) { v1 = ov; i1 = oi; }
    }
    float v2 = (lane == i1) ? -3.402823466e+38f : v;
    int   i2 = lane;
#pragma unroll
    for (int off = 32; off >= 1; off >>= 1) {
      const float ov = __shfl_xor(v2, off, 64);
      const int   oi = __shfl_xor(i2, off, 64);
      if (ov > v2 || (ov == v2 && oi < i2)) { v2 = ov; i2 = oi; }
    }

    if (lane == 0) {
      const int tok = tok0 + t;
      const float e2 = expf(v2 - v1);
      const float s  = 1.f + e2;
      out[2 * tok]     = 1.f / s;            // weights, descending like top_k
      out[2 * tok + 1] = e2 / s;
      out[2 * T + 2 * tok]     = (float)i1;  // idx section (float-encoded)
      out[2 * T + 2 * tok + 1] = (float)i2;
    }
  }
}

extern "C" void kernel_launch(void* const* d_in, const int* in_sizes, int n_in,
                              void* d_out, int out_size, void* d_ws, size_t ws_size,
                              hipStream_t stream) {
  const float* x  = (const float*)d_in[0];   // [4,8192,2048] f32
  const float* Wg = (const float*)d_in[1];   // [64,2048] f32
  const float* gb = (const float*)d_in[2];   // [64] f32
  float* out = (float*)d_out;                // [2*T weights][2*T idx-as-float]
  const int T = in_sizes[0] / HIDDEN;        // 32768 tokens
  router_kernel<<<dim3(T / TPBK), dim3(TPB), 0, stream>>>(x, Wg, gb, out, T);
}